// Round 1
// baseline (67.480 us; speedup 1.0000x reference)
//
#include <hip/hip_runtime.h>

#define I0F 5.6e-06f

// ---------------------------------------------------------------------------
// R6: ws-free redundant-scan design.
//
// Theory for this revision: the previous handshake kernel used d_ws as a
// mailbox. rocprof shows per-iteration __amd_rocclr_fillBufferAligned
// dispatches writing 256 MiB (= ws_size) at ~40.5 us — the harness's
// workspace re-poison — and our kernel itself is NOT in the top-5 (<40 us).
// 66 us ~= 40.5 (ws poison in the timed region) + ~25 (kernel + handshake).
// Using d_ws is what drags that poison into the timed loop. So: no ws at all.
//
// Structure: EVERY block redundantly runs the 64-wide chunked scan.
// Determinism: same inputs, same float ops, same order -> bit-identical
// (i, r, s, y, t_stop) in every block; no communication needed. The scan is
// ~2-3 us of serial FMA chain on ~7 KB of x (L2-broadcast friendly).
//   - Block 0's wave 0 additionally stores the prefix out[0..t_stop).
//   - Each block shares {y_final, t_stop} with its other 3 waves via LDS.
//   - All 65536 threads then fill out[t_stop..T) with y_final, one float4
//     per thread (1 MiB total).
//
// Scan per 64-step chunk (unchanged from verified R3-R5 math): 64 lanes load
// rows t-1+lane (coalesced 24 B/lane), dot with b in parallel; prefetch next
// chunk; broadcast 64 ct via __shfl; run the 64-step recurrence redundantly
// in all lanes:
//   i2 = fma(i*c, s, i*(1-k)); r2 = fma(k,i,r); s = (1-r2)-i2; y = i2+r2
// lane u latches step u's y; one coalesced store per chunk (block 0 only).
//
// Early-stop soundness (unchanged, measured absmax 0.0 in R3-R5): x in [0,1)
// => c_t <= cb := sum_j max(b_j,0); r monotone => future s <= 1-r. Stop when
// i==0 (frozen exactly) or i < 1e-5 and cb*(1-r) < 0.9*k: future factor
// <= 1-0.1k < 1 (geometric decay forever), total future |dy|
// <= i*cb*(1-r)/(k-cb*(1-r)) <= 9e-5 << 1.83e-2 threshold.
//
// Fallback: if no convergence, block 0's scalar tail writes ALL of out and
// t_stop = T, making every fill loop empty. No correctness dependence on
// convergence.
// ---------------------------------------------------------------------------
__global__ __launch_bounds__(256) void sir_kernel(const float* __restrict__ x,
                                                  const float* __restrict__ bv,
                                                  const float* __restrict__ kv,
                                                  float* __restrict__ out,
                                                  int T) {
    __shared__ float sh_y;
    __shared__ int   sh_tstop;

    if (threadIdx.x < 64) {
        const int lane = threadIdx.x;

        const float b0 = bv[0], b1 = bv[1], b2 = bv[2], b3 = bv[3], b4 = bv[4], b5 = bv[5];
        const float kq  = fabsf(kv[0]);
        const float omk = 1.0f - kq;
        const float cb  = fmaxf(b0, 0.0f) + fmaxf(b1, 0.0f) + fmaxf(b2, 0.0f) +
                          fmaxf(b3, 0.0f) + fmaxf(b4, 0.0f) + fmaxf(b5, 0.0f);
        const float thr = 0.90f * kq;

        const bool writer = (blockIdx.x == 0);

        float i = I0F;
        float r = 0.0f;
        float s = 1.0f - I0F;
        float y = I0F;                 // y_0 = i_0 + r_0 = i0
        if (writer && lane == 0) out[0] = y;

        int  t      = 1;
        int  t_stop = T;
        bool done   = false;

        auto loadRow = [&](int row, float2& p0, float2& p1, float2& p2) {
            const float2* rp = reinterpret_cast<const float2*>(x + (size_t)row * 6);
            p0 = rp[0]; p1 = rp[1]; p2 = rp[2];
        };
        auto dot = [&](float2 p0, float2 p1, float2 p2) {
            return p0.x * b0 + p0.y * b1 + p1.x * b2 + p1.y * b3 + p2.x * b4 + p2.y * b5;
        };

        float ct = 0.0f;
        if (t + 64 <= T) {
            float2 q0, q1, q2;
            loadRow(t - 1 + lane, q0, q1, q2);     // rows t-1 .. t+62, all < T
            ct = dot(q0, q1, q2);
        }

        while (t + 64 <= T) {
            const bool have_next = (t + 128 <= T);
            float2 n0, n1, n2;
            if (have_next) loadRow(t + 63 + lane, n0, n1, n2);

            float cts[64];
#pragma unroll
            for (int u = 0; u < 64; ++u) cts[u] = __shfl(ct, u, 64);

            float ykeep = 0.0f;
#pragma unroll
            for (int u = 0; u < 64; ++u) {
                const float c  = cts[u];
                const float a  = i * c;
                const float i2 = fmaf(a, s, i * omk);       // i + i*c*s - k*i
                const float r2 = fmaf(kq, i, r);            // r + k*i
                s = (1.0f - r2) - i2;
                y = i2 + r2;
                i = i2;
                r = r2;
                ykeep = (lane == u) ? y : ykeep;            // latch step u's y in lane u
            }
            if (writer) out[t + lane] = ykeep;              // one coalesced store/chunk
            t += 64;

            if (i == 0.0f || (i < 1e-5f && cb * (1.0f - r) < thr)) {
                t_stop = t;
                done   = true;
                break;
            }
            if (!have_next) break;
            ct = dot(n0, n1, n2);
        }

        if (!done) {
            // scalar tail (partial final chunk, or full fallback if no convergence)
            while (t < T) {
                const float2* rp = reinterpret_cast<const float2*>(x + (size_t)(t - 1) * 6);
                const float2 p0 = rp[0], p1 = rp[1], p2 = rp[2];
                const float c  = dot(p0, p1, p2);
                const float a  = i * c;
                const float i2 = fmaf(a, s, i * omk);
                const float r2 = fmaf(kq, i, r);
                s = (1.0f - r2) - i2;
                y = i2 + r2;
                i = i2;
                r = r2;
                if (writer && lane == 0) out[t] = y;
                ++t;
            }
            t_stop = T;
        }

        if (lane == 0) { sh_y = y; sh_tstop = t_stop; }
    }
    __syncthreads();

    const float yf     = sh_y;
    const int   t_stop = sh_tstop;

    // Boundary scalars [t_stop, t4) and any ragged tail [Tv, T): block 0 only
    // (at most 3 + 3 elements). Both ranges are empty in the fallback case
    // (t_stop == T) and when T % 4 == 0 respectively.
    const int t4 = (t_stop + 3) & ~3;
    const int Tv = T & ~3;
    if (blockIdx.x == 0) {
        const int bend = t4 < T ? t4 : T;
        for (int idx = t_stop + (int)threadIdx.x; idx < bend; idx += 256) out[idx] = yf;
        const int tstart = Tv > t_stop ? Tv : t_stop;
        for (int idx = tstart + (int)threadIdx.x; idx < T; idx += 256) out[idx] = yf;
    }

    // Vectorized fill [t4, Tv): one float4 per thread across the whole grid.
    if (t4 < Tv) {
        float4* o4 = reinterpret_cast<float4*>(out);
        const float4 v4 = make_float4(yf, yf, yf, yf);
        const int qend = Tv >> 2;
        const int qstr = (int)(gridDim.x * blockDim.x);
        for (int q = (t4 >> 2) + (int)(blockIdx.x * blockDim.x + threadIdx.x);
             q < qend; q += qstr)
            o4[q] = v4;
    }
}

extern "C" void kernel_launch(void* const* d_in, const int* in_sizes, int n_in,
                              void* d_out, int out_size, void* d_ws, size_t ws_size,
                              hipStream_t stream) {
    const float* x = (const float*)d_in[0];   // [T,6] f32
    const float* b = (const float*)d_in[1];   // [6,1] f32
    const float* k = (const float*)d_in[2];   // [1,1] f32
    float* out = (float*)d_out;               // [1,T] f32
    int T = out_size;                         // 262144

    // d_ws deliberately unused: no workspace state, no re-poison dependency.
    (void)d_ws; (void)ws_size;

    sir_kernel<<<256, 256, 0, stream>>>(x, b, k, out, T);
}